// Round 14
// baseline (330.075 us; speedup 1.0000x reference)
//
#include <hip/hip_runtime.h>
#include <hip/hip_bf16.h>

// MultiScaleRetention forward. Inputs/outputs FLOAT32; internals bf16 MFMA.
//   0) convert x -> xb (bf16); transpose weights f32 -> bf16
//   1) GEMM1: xb @ Wt^T, BK=128 2-phase loop (R21: second barrier-halving;
//      m132's hazard N/A because occupancy already pinned at 2 blocks/CU and
//      2x64KB=128KB <= 160KB). Staging = 4-row x 128-k 1KB ASYNC16 chunks,
//      16-granule rotation swizzle (slot=(g+row)&15; row stride 256B == 0
//      mod 32 banks -> bank set from slot alone -> 2-way/free). Fragments
//      read per-kk (VGPR-lean). K ascending -> bit-identical accumulation.
//      LEAN epilogue unchanged: qk -> f32 Cqk (+bias,+k-scale); V -> bf16
//      FRAGMENT layout (R17-proven); g -> f32.
//   2) router: rotary (f32) + hi/lo bf16 split + (bh,S,64) layout for q,k
//      (R19 fuse REVERTED: 2B scatter stores = 48x HBM write amplification)
//   3) retention R18 (proven ~98us): block = (bh, 4 consecutive 16-row
//      stripes), 4 waves x 1 stripe each, LDS-staged K + V direct-to-reg.
//   4) GEMM2: gated @ oT^T + o_b -> d_out (f32), same BK=128 loop (48KB LDS).
// absmax canary: 0.01049805 exactly (all FP orders preserved).
// History: R20 (BK=64) 339->318us; R19 reverted; session best = this line.

typedef __hip_bfloat16 bf16;
typedef short bf16x4 __attribute__((ext_vector_type(4)));
typedef short bf16x8 __attribute__((ext_vector_type(8)));
typedef float floatx4 __attribute__((ext_vector_type(4)));

#define B_SZ 2
#define SEQ 2048
#define NH 16
#define KD 64
#define HD 128

// global->LDS direct copy, 16B/lane. LDS dest is wave-uniform base + lane*16.
#define ASYNC16(gp, lp)                                                             \
  __builtin_amdgcn_global_load_lds(                                                 \
      (const __attribute__((address_space(1))) unsigned int*)(unsigned long long)(const void*)(gp), \
      (__attribute__((address_space(3))) unsigned int*)(unsigned int)(unsigned long long)(void*)(lp), \
      16, 0, 0)

__device__ __forceinline__ float b2f(bf16 x) { return __bfloat162float(x); }
__device__ __forceinline__ bf16 f2b(float x) { return __float2bfloat16(x); }

#define MFMA16(a, bb, c) __builtin_amdgcn_mfma_f32_16x16x32_bf16(a, bb, c, 0, 0, 0)

// ---------------- f32 -> bf16 convert (x) ----------------
__global__ void convert_k(const float* __restrict__ in, bf16* __restrict__ out) {
  int i = blockIdx.x * 256 + threadIdx.x;  // one float4 per thread
  float4 v = reinterpret_cast<const float4*>(in)[i];
  union { bf16 h[4]; bf16x4 v4; } u;
  u.h[0] = f2b(v.x); u.h[1] = f2b(v.y); u.h[2] = f2b(v.z); u.h[3] = f2b(v.w);
  reinterpret_cast<bf16x4*>(out)[i] = u.v4;
}

// ---------------- weight transpose: in f32 (K,N) -> out bf16 (N,K) --------
__global__ void transpose_k(const float* __restrict__ in, bf16* __restrict__ out,
                            int K, int N) {
  __shared__ float tile[32][33];
  int tx = threadIdx.x, ty = threadIdx.y;
  int n0 = blockIdx.x * 32, k0 = blockIdx.y * 32;
#pragma unroll
  for (int j = 0; j < 4; ++j)
    tile[ty + j * 8][tx] = in[(size_t)(k0 + ty + j * 8) * N + n0 + tx];
  __syncthreads();
#pragma unroll
  for (int j = 0; j < 4; ++j)
    out[(size_t)(n0 + ty + j * 8) * K + k0 + tx] = f2b(tile[tx][ty + j * 8]);
}

// ---------------- GEMM: C(M,N) = A(M,K) @ Bt(N,K)^T ----------------
// R21 loop: BK=128. LDS [row][128] bf16. Staging: chunk cc = 4 rows x 128 k
// = 1KB; lane L -> row cc*4+(L>>4), source granule q=((L&15)-row)&15 (LDS
// slot s holds granule (s-row)&15). Fragment read for k-granule g=kk*4+quad
// at row r -> slot (g+r)&15. Per-kk fragment reads + MFMA (kk=0..3
// ascending K -> bit-identical accumulation).
// MODE 0 epilogue: qk -> f32 Cqk; V -> bf16 FRAGMENT layout; g -> f32.
template <int BM, int BN, int KDIM, int MODE>
__global__ __launch_bounds__(256, 2) void gemm_bt(
    const bf16* __restrict__ A, const bf16* __restrict__ Bt, int Ndim,
    const float* __restrict__ bias_q, const float* __restrict__ bias_k,
    const float* __restrict__ bias_v, const float* __restrict__ bias_g,
    float* __restrict__ outCqk, bf16* __restrict__ out_v,
    float* __restrict__ out_g, float* __restrict__ outF) {
  __shared__ bf16 As[BM * 128];
  __shared__ bf16 Bs[BN * 128];
  const int tid = threadIdx.x;
  const int wave = tid >> 6, lane = tid & 63;
  const int quad = lane >> 4, l16 = lane & 15;
  const int m0 = blockIdx.y * BM, n0 = blockIdx.x * BN;
  constexpr int FI = BM / 32;
  constexpr int FJ = BN / 32;
  const int wm = (wave >> 1) * (BM / 2), wn = (wave & 1) * (BN / 2);

  floatx4 acc[FI][FJ] = {};

  for (int k0 = 0; k0 < KDIM; k0 += 128) {
#pragma unroll
    for (int j = 0; j < BM / 16; ++j) {
      int cc = wave * (BM / 16) + j;       // 0..BM/4-1
      int row = cc * 4 + (lane >> 4);
      int q = ((lane & 15) - row) & 15;
      ASYNC16(A + (size_t)(m0 + row) * KDIM + k0 + q * 8, &As[cc * 512]);
    }
#pragma unroll
    for (int j = 0; j < BN / 16; ++j) {
      int cc = wave * (BN / 16) + j;       // 0..BN/4-1
      int row = cc * 4 + (lane >> 4);
      int q = ((lane & 15) - row) & 15;
      ASYNC16(Bt + (size_t)(n0 + row) * KDIM + k0 + q * 8, &Bs[cc * 512]);
    }
    __syncthreads();  // compiler drains vmcnt(0) before s_barrier

#pragma unroll
    for (int kk = 0; kk < 4; ++kk) {
      bf16x8 af[FI], bfr[FJ];
#pragma unroll
      for (int i = 0; i < FI; ++i) {
        int row = wm + i * 16 + l16;
        int slot = ((kk * 4 + quad) + row) & 15;
        af[i] = *(const bf16x8*)&As[row * 128 + slot * 8];
      }
#pragma unroll
      for (int j = 0; j < FJ; ++j) {
        int row = wn + j * 16 + l16;
        int slot = ((kk * 4 + quad) + row) & 15;
        bfr[j] = *(const bf16x8*)&Bs[row * 128 + slot * 8];
      }
#pragma unroll
      for (int i = 0; i < FI; ++i)
#pragma unroll
        for (int j = 0; j < FJ; ++j)
          acc[i][j] = MFMA16(af[i], bfr[j], acc[i][j]);
    }
    __syncthreads();
  }

  // LEAN epilogue, all stores coalesced (unchanged)
#pragma unroll
  for (int i = 0; i < FI; ++i) {
#pragma unroll
    for (int j = 0; j < FJ; ++j) {
      int gn = n0 + wn + j * 16 + l16;
      if (MODE == 0 && gn >= 2048 && gn < 4096) {
        // V -> fragment layout, one 8B packed store (4 consecutive s)
        int jj = gn - 2048;
        int s0 = m0 + wm + i * 16 + quad * 4;  // 4-aligned
        union { bf16 e[4]; unsigned long long u8; } pk;
#pragma unroll
        for (int r = 0; r < 4; ++r) pk.e[r] = f2b(acc[i][j][r] + bias_v[jj]);
        int b2 = s0 >> 11, srel = s0 & 2047;
        int h2 = jj >> 7, dloc = jj & 127;
        size_t bh2 = (size_t)b2 * NH + h2;
        size_t idx = ((bh2 * 64 + (srel >> 5)) * 8 + (dloc >> 4)) * 512 +
                     (size_t)(((srel >> 3) & 3) * 16 + (dloc & 15)) * 8 +
                     (srel & 7);
        *(unsigned long long*)&out_v[idx] = pk.u8;
      } else {
#pragma unroll
        for (int r = 0; r < 4; ++r) {
          int gm = m0 + wm + i * 16 + quad * 4 + r;
          float v = acc[i][j][r];
          if (MODE == 1) {
            v += bias_q[gn];  // bias_q = o_b
            outF[(size_t)gm * Ndim + gn] = v;
          } else {
            if (gn < 2048) {
              bool is_k = gn >= 1024;
              int jj = is_k ? gn - 1024 : gn;
              v += is_k ? bias_k[jj] : bias_q[jj];
              if (is_k) v *= 0.125f;  // SCALING = KEY_DIM^-0.5
              outCqk[(size_t)gm * 2048 + gn] = v;  // f32, exact
            } else {
              int jj = gn - 4096;
              v += bias_g[jj];
              out_g[(size_t)gm * 2048 + jj] = v;  // f32
            }
          }
        }
      }
    }
  }
}

// ---------------- router: rotary + hi/lo split + layout (R12 version) -----
__global__ void router_k(const float* __restrict__ Cqk,
                         bf16* __restrict__ qh, bf16* __restrict__ ql,
                         bf16* __restrict__ kh, bf16* __restrict__ kl) {
  int t = blockIdx.x * 256 + threadIdx.x;  // 4096*1024 threads
  int row = t >> 10, pc = t & 1023;
  int b = row >> 11, s = row & 2047;
  bool is_k = pc >= 512;
  int jj = (pc - (is_k ? 512 : 0)) * 2;  // even, 0..1022
  int h = jj >> 6, d = jj & 63, ii = d >> 1;
  float2 v = *(const float2*)&Cqk[(size_t)row * 2048 + pc * 2];
  float half = exp2f(-(float)ii * (13.287712379549449f / 31.0f));
  float ang = (float)s * half;
  float sn = sinf(ang), cs = cosf(ang);
  float e = v.x * cs - v.y * sn;
  float o = v.y * cs + v.x * sn;
  bf16 eh = f2b(e), oh = f2b(o);
  bf16 el = f2b(e - b2f(eh)), ol = f2b(o - b2f(oh));
  size_t idx = (((size_t)b * NH + h) * SEQ + s) * KD + d;
  bf16* ph = is_k ? kh : qh;
  bf16* pl = is_k ? kl : ql;
  union { bf16 h2[2]; unsigned u; } uh, ul;
  uh.h2[0] = eh; uh.h2[1] = oh;
  ul.h2[0] = el; ul.h2[1] = ol;
  *(unsigned*)&ph[idx] = uh.u;
  *(unsigned*)&pl[idx] = ul.u;
}

// ---------------- retention core (R18, proven ~98us) ----------
// grid 1024 x 256. bid: bh = bid>>5 (h=bh&15, b=bh>>4), grp_raw = bid&31,
// grp = (bh bit3) ? 31-grp_raw : grp_raw (co-resident slot balancing).
// Wave w owns stripe st = grp*4 + w (16 rows, m0 = st*16), iterating its
// causal prefix inside the block's ntiles = 2*grp+2 loop. K hi/lo staged in
// LDS (double-buffered ASYNC16, 2 chunks/wave), shared by all 4 waves; V
// per-wave direct global->reg (fragment buffer). Per-stripe math/order
// identical to R15 heavy path -> canary preserved.
__global__ __launch_bounds__(256, 4) void retention_k(
    const bf16* __restrict__ qh, const bf16* __restrict__ ql,
    const bf16* __restrict__ kh, const bf16* __restrict__ kl,
    const bf16* __restrict__ vf, const float* __restrict__ g,
    bf16* __restrict__ gated) {
  __shared__ bf16 KHs[2][32 * 64];
  __shared__ bf16 KLs[2][32 * 64];
  const int tid = threadIdx.x;
  const int wave = tid >> 6, lane = tid & 63;
  const int quad = lane >> 4, l16 = lane & 15;
  const int bid = blockIdx.x;
  const int grp_raw = bid & 31;
  const int bh = bid >> 5;            // 0..31
  const int h = bh & 15, b = bh >> 4;
  const int grp = ((bh >> 3) & 1) ? (31 - grp_raw) : grp_raw;
  const int st = grp * 4 + wave;      // stripe 0..127
  const int m0 = st * 16;
  const int ntiles = 2 * grp + 2;     // block loop count (= longest wave)

  const float t = exp2f(-(float)(5 + h));  // 1-gamma (exact)
  const float lng = log1pf(-t);            // ln(gamma)
  const float log2g = lng * 1.44269504088896340736f;

  float rf;
  {
    int m = m0 + l16;
    rf = exp2f((float)m * log2g) *
         rsqrtf(-expm1f((float)(m + 1) * lng) / t);
  }
  const float gstep = exp2f(-32.0f * log2g);  // gamma^-32
  float cfq[8];
#pragma unroll
  for (int i = 0; i < 8; ++i) {
    int hh = i >> 2, r = i & 3;
    cfq[i] = exp2f(-(float)(hh * 16 + quad * 4 + r) * log2g);
  }

  const size_t qoff = ((size_t)bh * SEQ + m0 + l16) * KD;
  bf16x8 aq0h = *(const bf16x8*)&qh[qoff + quad * 8];
  bf16x8 aq1h = *(const bf16x8*)&qh[qoff + 32 + quad * 8];
  bf16x8 aq0l = *(const bf16x8*)&ql[qoff + quad * 8];
  bf16x8 aq1l = *(const bf16x8*)&ql[qoff + 32 + quad * 8];

  floatx4 oacc[8] = {};
  float rs = 0.f;

  const bf16* khb = kh + (size_t)bh * SEQ * KD;
  const bf16* klb = kl + (size_t)bh * SEQ * KD;
  const bf16* vfb = vf + (size_t)bh * 64 * 8 * 512;
  const int lo8 = lane * 8;

  // K staging: 8 x 1KB chunks per tile over 4 waves (2 each):
  // cc<4 -> KH chunk cc, else KL chunk cc-4. Same swizzle as R12/R15.
  auto stage = [&](int nt, int buf) {
    const int n0s = nt * 32;
#pragma unroll
    for (int j = 0; j < 2; ++j) {
      int cc = wave * 2 + j;
      const bf16* src = (cc < 4) ? khb : klb;
      bf16* dst = (cc < 4) ? KHs[buf] : KLs[buf];
      int r = ((cc & 3) * 8) + (lane >> 3);
      int s = lane & 7;
      int q = (s - r) & 7;
      ASYNC16(src + (size_t)(n0s + r) * KD + q * 8, &dst[(cc & 3) * 512]);
    }
  };

  // Build PV A-frag in-register from the transposed score tile (as R12/R15).
  auto buildPA = [&](const floatx4* sc, int n0) -> bf16x8 {
    const int m = m0 + l16;
    const bool full = (m0 >= n0 + 31);  // tile fully below diagonal
    unsigned d[4];
#pragma unroll
    for (int hh = 0; hh < 2; ++hh) {
      float p[4];
#pragma unroll
      for (int r = 0; r < 4; ++r) {
        float pv;
        if (full) {
          pv = sc[hh][r] * rf * cfq[hh * 4 + r];
        } else {
          int n = n0 + hh * 16 + quad * 4 + r;
          pv = (m >= n) ? sc[hh][r] * rf * cfq[hh * 4 + r] : 0.f;
        }
        rs += pv;
        p[r] = pv;
      }
      union { bf16 hx[2]; unsigned u; } u0, u1;
      u0.hx[0] = f2b(p[0]); u0.hx[1] = f2b(p[1]);
      u1.hx[0] = f2b(p[2]); u1.hx[1] = f2b(p[3]);
      d[hh * 2 + 0] = u0.u;
      d[hh * 2 + 1] = u1.u;
    }
    unsigned a0 = d[0], b0 = d[2];  // (hh0 pair01, hh1 pair01)
    asm("v_permlane32_swap_b32 %0, %1" : "+v"(a0), "+v"(b0));
    asm("v_permlane16_swap_b32 %0, %1" : "+v"(a0), "+v"(b0));
    unsigned a1 = d[1], b1 = d[3];  // (hh0 pair23, hh1 pair23)
    asm("v_permlane32_swap_b32 %0, %1" : "+v"(a1), "+v"(b1));
    asm("v_permlane16_swap_b32 %0, %1" : "+v"(a1), "+v"(b1));
    union { unsigned u[4]; bf16x8 v; } pu;
    pu.u[0] = a0; pu.u[1] = a1; pu.u[2] = b0; pu.u[3] = b1;
    return pu.v;
  };

  stage(0, 0);
  for (int nt = 0; nt < ntiles; ++nt) {
    const int n0 = nt * 32;
    const int cur = nt & 1;
    asm volatile("s_waitcnt vmcnt(0) lgkmcnt(0)" ::: "memory");
    __syncthreads();

    const bool act = (n0 <= m0 + 15);

    // V tile direct to registers (only while this wave's stripe is active)
    bf16x8 vv[8];
    if (act) {
#pragma unroll
      for (int c = 0; c < 8; ++c)
        vv[c] = *(const bf16x8*)(vfb + ((size_t)nt * 8 + c) * 512 + lo8);
    }

    {
      int pf = (nt + 1 < ntiles) ? nt + 1 : nt;
      stage(pf, cur ^ 1);
    }

    if (act) {
      // QK (SWAPPED: A=K-frag, B=Q-frag) — identical to R15 heavy path
      floatx4 sc[2];
#pragma unroll
      for (int hh = 0; hh < 2; ++hh) {
        int krow = hh * 16 + l16;
        int c0 = ((quad + krow) & 7) * 8;
        int c1 = ((quad + 4 + krow) & 7) * 8;
        bf16x8 bkh0 = *(const bf16x8*)&KHs[cur][krow * 64 + c0];
        bf16x8 bkh1 = *(const bf16x8*)&KHs[cur][krow * 64 + c1];
        bf16x8 bkl0 = *(const bf16x8*)&KLs[cur][krow * 64 + c0];
        bf16x8 bkl1 = *(const bf16x8*)&KLs[cur][krow * 64 + c1];
        floatx4 z1 = {0.f, 0.f, 0.f, 0.f}, z2 = z1, z3 = z1;
        z1 = MFMA16(bkh0, aq0h, z1);
        z2 = MFMA16(bkh0, aq0l, z2);
        z3 = MFMA16(bkl0, aq0h, z3);
        z1 = MFMA16(bkh1, aq1h, z1);
        z2 = MFMA16(bkh1, aq1l, z2);
        z3 = MFMA16(bkl1, aq1h, z3);
        sc[hh] = z1 + z2 + z3;
      }

      bf16x8 pa = buildPA(sc, n0);
      rf *= gstep;

#pragma unroll
      for (int dt = 0; dt < 8; ++dt)
        oacc[dt] = MFMA16(pa, vv[dt], oacc[dt]);
    }
  }

  // ---- epilogue: denom clip, groupnorm(128), silu gate ----
  {
    float v = rs;
    v += __shfl_xor(v, 16);
    v += __shfl_xor(v, 32);
    float inv_den[4];
#pragma unroll
    for (int r = 0; r < 4; ++r) {
      float dsum = __shfl(v, quad * 4 + r);
      inv_den[r] = 1.0f / fmaxf(fabsf(dsum), 1.0f);
    }
    float s1[4] = {}, s2[4] = {};
#pragma unroll
    for (int dt = 0; dt < 8; ++dt) {
#pragma unroll
      for (int r = 0; r < 4; ++r) {
        float vv2 = oacc[dt][r] * inv_den[r];
        oacc[dt][r] = vv2;
        s1[r] += vv2;
        s2[r] += vv2 * vv2;
      }
    }
    float mean[4], istd[4];
#pragma unroll
    for (int r = 0; r < 4; ++r) {
      float a = s1[r], q2 = s2[r];
      a += __shfl_xor(a, 1); a += __shfl_xor(a, 2);
      a += __shfl_xor(a, 4); a += __shfl_xor(a, 8);
      q2 += __shfl_xor(q2, 1); q2 += __shfl_xor(q2, 2);
      q2 += __shfl_xor(q2, 4); q2 += __shfl_xor(q2, 8);
      mean[r] = a * (1.0f / 128.0f);
      float var = q2 * (1.0f / 128.0f) - mean[r] * mean[r];
      istd[r] = rsqrtf(fmaxf(var, 0.0f) + 1e-5f);
    }
#pragma unroll
    for (int dt = 0; dt < 8; ++dt) {
#pragma unroll
      for (int r = 0; r < 4; ++r) {
        int m = m0 + quad * 4 + r;
        int col = h * HD + dt * 16 + l16;
        float vv2 = (oacc[dt][r] - mean[r]) * istd[r];
        float gv = g[((size_t)b * SEQ + m) * 2048 + col];
        float sg = gv / (1.0f + expf(-gv));
        gated[((size_t)b * SEQ + m) * 2048 + col] = f2b(sg * vv2);
      }
    }
  }
}

// ---------------- launch ----------------
extern "C" void kernel_launch(void* const* d_in, const int* in_sizes, int n_in,
                              void* d_out, int out_size, void* d_ws,
                              size_t ws_size, hipStream_t stream) {
  const float* x   = (const float*)d_in[0];
  const float* q_w = (const float*)d_in[1];
  const float* q_b = (const float*)d_in[2];
  const float* k_w = (const float*)d_in[3];
  const float* k_b = (const float*)d_in[4];
  const float* v_w = (const float*)d_in[5];
  const float* v_b = (const float*)d_in[6];
  const float* g_w = (const float*)d_in[7];
  const float* g_b = (const float*)d_in[8];
  const float* o_w = (const float*)d_in[9];
  const float* o_b = (const float*)d_in[10];

  char* ws = (char*)d_ws;
  bf16* Wt    = (bf16*)ws; ws += (size_t)6144 * 1024 * 2;
  bf16* oT    = (bf16*)ws; ws += (size_t)1024 * 2048 * 2;
  bf16* xb    = (bf16*)ws; ws += (size_t)4096 * 1024 * 2;
  float* Cqk  = (float*)ws; ws += (size_t)4096 * 2048 * 4;
  bf16* qhb   = (bf16*)ws; ws += (size_t)32 * 2048 * 64 * 2;
  bf16* qlb   = (bf16*)ws; ws += (size_t)32 * 2048 * 64 * 2;
  bf16* khb   = (bf16*)ws; ws += (size_t)32 * 2048 * 64 * 2;
  bf16* klb   = (bf16*)ws; ws += (size_t)32 * 2048 * 64 * 2;
  bf16* vfb   = (bf16*)ws; ws += (size_t)32 * 64 * 8 * 512 * 2;  // 16.78 MB V frags
  float* gbuf = (float*)ws; ws += (size_t)2 * 2048 * 2048 * 4;
  bf16* gated = (bf16*)ws; ws += (size_t)4096 * 2048 * 2;

  convert_k<<<(4096 * 1024 / 4) / 256, 256, 0, stream>>>(x, xb);

  dim3 tb(32, 8);
  transpose_k<<<dim3(1024 / 32, 1024 / 32), tb, 0, stream>>>(q_w, Wt, 1024, 1024);
  transpose_k<<<dim3(1024 / 32, 1024 / 32), tb, 0, stream>>>(k_w, Wt + (size_t)1024 * 1024, 1024, 1024);
  transpose_k<<<dim3(2048 / 32, 1024 / 32), tb, 0, stream>>>(v_w, Wt + (size_t)2048 * 1024, 1024, 2048);
  transpose_k<<<dim3(2048 / 32, 1024 / 32), tb, 0, stream>>>(g_w, Wt + (size_t)4096 * 1024, 1024, 2048);
  transpose_k<<<dim3(1024 / 32, 2048 / 32), tb, 0, stream>>>(o_w, oT, 2048, 1024);

  // GEMM1 writes V directly in fragment layout (vtrans fused away)
  gemm_bt<128, 128, 1024, 0><<<dim3(6144 / 128, 4096 / 128), 256, 0, stream>>>(
      xb, Wt, 6144, q_b, k_b, v_b, g_b, Cqk, vfb, gbuf, nullptr);

  router_k<<<(4096 * 1024) / 256, 256, 0, stream>>>(Cqk, qhb, qlb, khb, klb);

  retention_k<<<dim3(1024), 256, 0, stream>>>(
      qhb, qlb, khb, klb, vfb, gbuf, gated);

  gemm_bt<128, 64, 2048, 1><<<dim3(1024 / 64, 4096 / 128), 256, 0, stream>>>(
      gated, oT, 1024, o_b, nullptr, nullptr, nullptr, nullptr, nullptr,
      nullptr, (float*)d_out);
}

// Round 15
// 329.661 us; speedup vs baseline: 1.0013x; 1.0013x over previous
//
#include <hip/hip_runtime.h>
#include <hip/hip_bf16.h>

// MultiScaleRetention forward. Inputs/outputs FLOAT32; internals bf16 MFMA.
//   0) convert x -> xb (bf16); transpose weights f32 -> bf16
//   1) GEMM1: xb @ Wt^T, BK=64 2-phase loop (R20: half the barrier-drain
//      events of BK=32, 2x MFMA per phase). Staging = 8-row x 64-k 1KB
//      ASYNC16 chunks with rotation-swizzled source granule (q=(s-row)&7)
//      so 128B-stride ds_read_b128 fragment reads are 2-way/free. K order
//      ascending -> bit-identical results. LEAN epilogue: qk -> f32 Cqk
//      (+bias,+k-scale); V -> bf16 FRAGMENT layout (R17); g -> f32.
//   2) router: rotary (f32) + hi/lo bf16 split + (bh,S,64) layout for q,k
//      (R19 fuse REVERTED: 2B scatter stores = 48x HBM write amplification)
//   3) retention R18 (proven ~98us): block = (bh, 4 consecutive 16-row
//      stripes), 4 waves x 1 stripe each, LDS-staged K + V direct-to-reg.
//   4) GEMM2: gated @ oT^T + o_b -> d_out (f32), same BK=64 loop.
// absmax canary: 0.01049805 exactly (all FP orders preserved).
// History: R20 = session best 318.0us. R21 (BK=128) regressed to 330
// (6.29M LDS bank conflicts + longer stage latency) -> reverted here.

typedef __hip_bfloat16 bf16;
typedef short bf16x4 __attribute__((ext_vector_type(4)));
typedef short bf16x8 __attribute__((ext_vector_type(8)));
typedef float floatx4 __attribute__((ext_vector_type(4)));

#define B_SZ 2
#define SEQ 2048
#define NH 16
#define KD 64
#define HD 128

// global->LDS direct copy, 16B/lane. LDS dest is wave-uniform base + lane*16.
#define ASYNC16(gp, lp)                                                             \
  __builtin_amdgcn_global_load_lds(                                                 \
      (const __attribute__((address_space(1))) unsigned int*)(unsigned long long)(const void*)(gp), \
      (__attribute__((address_space(3))) unsigned int*)(unsigned int)(unsigned long long)(void*)(lp), \
      16, 0, 0)

__device__ __forceinline__ float b2f(bf16 x) { return __bfloat162float(x); }
__device__ __forceinline__ bf16 f2b(float x) { return __float2bfloat16(x); }

#define MFMA16(a, bb, c) __builtin_amdgcn_mfma_f32_16x16x32_bf16(a, bb, c, 0, 0, 0)

// ---------------- f32 -> bf16 convert (x) ----------------
__global__ void convert_k(const float* __restrict__ in, bf16* __restrict__ out) {
  int i = blockIdx.x * 256 + threadIdx.x;  // one float4 per thread
  float4 v = reinterpret_cast<const float4*>(in)[i];
  union { bf16 h[4]; bf16x4 v4; } u;
  u.h[0] = f2b(v.x); u.h[1] = f2b(v.y); u.h[2] = f2b(v.z); u.h[3] = f2b(v.w);
  reinterpret_cast<bf16x4*>(out)[i] = u.v4;
}

// ---------------- weight transpose: in f32 (K,N) -> out bf16 (N,K) --------
__global__ void transpose_k(const float* __restrict__ in, bf16* __restrict__ out,
                            int K, int N) {
  __shared__ float tile[32][33];
  int tx = threadIdx.x, ty = threadIdx.y;
  int n0 = blockIdx.x * 32, k0 = blockIdx.y * 32;
#pragma unroll
  for (int j = 0; j < 4; ++j)
    tile[ty + j * 8][tx] = in[(size_t)(k0 + ty + j * 8) * N + n0 + tx];
  __syncthreads();
#pragma unroll
  for (int j = 0; j < 4; ++j)
    out[(size_t)(n0 + ty + j * 8) * K + k0 + tx] = f2b(tile[tx][ty + j * 8]);
}

// ---------------- GEMM: C(M,N) = A(M,K) @ Bt(N,K)^T ----------------
// R20 loop: BK=64. LDS [row][64] bf16 (As BM*64, Bs BN*64). Staging: chunk
// cc = 8 rows x 64 k = 1KB; lane L -> row cc*8+(L>>3), granule q=((L&7)-row)&7
// (rotation swizzle; LDS slot s holds granule (s-row)&7). Fragment read for
// k-granule g=kk*4+quad at row r -> slot (g+r)&7: banks spread across rows,
// 2-way max. MFMA kk=0 then kk=1 -> ascending K, bit-identical accumulation.
// MODE 0 epilogue: qk -> f32 Cqk; V -> bf16 FRAGMENT layout; g -> f32.
template <int BM, int BN, int KDIM, int MODE>
__global__ __launch_bounds__(256, 2) void gemm_bt(
    const bf16* __restrict__ A, const bf16* __restrict__ Bt, int Ndim,
    const float* __restrict__ bias_q, const float* __restrict__ bias_k,
    const float* __restrict__ bias_v, const float* __restrict__ bias_g,
    float* __restrict__ outCqk, bf16* __restrict__ out_v,
    float* __restrict__ out_g, float* __restrict__ outF) {
  __shared__ bf16 As[BM * 64];
  __shared__ bf16 Bs[BN * 64];
  const int tid = threadIdx.x;
  const int wave = tid >> 6, lane = tid & 63;
  const int quad = lane >> 4, l16 = lane & 15;
  const int m0 = blockIdx.y * BM, n0 = blockIdx.x * BN;
  constexpr int FI = BM / 32;
  constexpr int FJ = BN / 32;
  const int wm = (wave >> 1) * (BM / 2), wn = (wave & 1) * (BN / 2);

  floatx4 acc[FI][FJ] = {};

  for (int k0 = 0; k0 < KDIM; k0 += 64) {
#pragma unroll
    for (int j = 0; j < BM / 32; ++j) {
      int cc = wave * (BM / 32) + j;       // 0..BM/8-1
      int row = cc * 8 + (lane >> 3);
      int q = ((lane & 7) - row) & 7;
      ASYNC16(A + (size_t)(m0 + row) * KDIM + k0 + q * 8, &As[cc * 512]);
    }
#pragma unroll
    for (int j = 0; j < BN / 32; ++j) {
      int cc = wave * (BN / 32) + j;       // 0..BN/8-1
      int row = cc * 8 + (lane >> 3);
      int q = ((lane & 7) - row) & 7;
      ASYNC16(Bt + (size_t)(n0 + row) * KDIM + k0 + q * 8, &Bs[cc * 512]);
    }
    __syncthreads();  // compiler drains vmcnt(0) before s_barrier

    bf16x8 af[2][FI], bfr[2][FJ];
#pragma unroll
    for (int kk = 0; kk < 2; ++kk) {
#pragma unroll
      for (int i = 0; i < FI; ++i) {
        int row = wm + i * 16 + l16;
        int slot = ((kk * 4 + quad) + row) & 7;
        af[kk][i] = *(const bf16x8*)&As[row * 64 + slot * 8];
      }
#pragma unroll
      for (int j = 0; j < FJ; ++j) {
        int row = wn + j * 16 + l16;
        int slot = ((kk * 4 + quad) + row) & 7;
        bfr[kk][j] = *(const bf16x8*)&Bs[row * 64 + slot * 8];
      }
    }
#pragma unroll
    for (int kk = 0; kk < 2; ++kk)
#pragma unroll
      for (int i = 0; i < FI; ++i)
#pragma unroll
        for (int j = 0; j < FJ; ++j)
          acc[i][j] = MFMA16(af[kk][i], bfr[kk][j], acc[i][j]);
    __syncthreads();
  }

  // LEAN epilogue, all stores coalesced (unchanged)
#pragma unroll
  for (int i = 0; i < FI; ++i) {
#pragma unroll
    for (int j = 0; j < FJ; ++j) {
      int gn = n0 + wn + j * 16 + l16;
      if (MODE == 0 && gn >= 2048 && gn < 4096) {
        // V -> fragment layout, one 8B packed store (4 consecutive s)
        int jj = gn - 2048;
        int s0 = m0 + wm + i * 16 + quad * 4;  // 4-aligned
        union { bf16 e[4]; unsigned long long u8; } pk;
#pragma unroll
        for (int r = 0; r < 4; ++r) pk.e[r] = f2b(acc[i][j][r] + bias_v[jj]);
        int b2 = s0 >> 11, srel = s0 & 2047;
        int h2 = jj >> 7, dloc = jj & 127;
        size_t bh2 = (size_t)b2 * NH + h2;
        size_t idx = ((bh2 * 64 + (srel >> 5)) * 8 + (dloc >> 4)) * 512 +
                     (size_t)(((srel >> 3) & 3) * 16 + (dloc & 15)) * 8 +
                     (srel & 7);
        *(unsigned long long*)&out_v[idx] = pk.u8;
      } else {
#pragma unroll
        for (int r = 0; r < 4; ++r) {
          int gm = m0 + wm + i * 16 + quad * 4 + r;
          float v = acc[i][j][r];
          if (MODE == 1) {
            v += bias_q[gn];  // bias_q = o_b
            outF[(size_t)gm * Ndim + gn] = v;
          } else {
            if (gn < 2048) {
              bool is_k = gn >= 1024;
              int jj = is_k ? gn - 1024 : gn;
              v += is_k ? bias_k[jj] : bias_q[jj];
              if (is_k) v *= 0.125f;  // SCALING = KEY_DIM^-0.5
              outCqk[(size_t)gm * 2048 + gn] = v;  // f32, exact
            } else {
              int jj = gn - 4096;
              v += bias_g[jj];
              out_g[(size_t)gm * 2048 + jj] = v;  // f32
            }
          }
        }
      }
    }
  }
}

// ---------------- router: rotary + hi/lo split + layout (R12 version) -----
__global__ void router_k(const float* __restrict__ Cqk,
                         bf16* __restrict__ qh, bf16* __restrict__ ql,
                         bf16* __restrict__ kh, bf16* __restrict__ kl) {
  int t = blockIdx.x * 256 + threadIdx.x;  // 4096*1024 threads
  int row = t >> 10, pc = t & 1023;
  int b = row >> 11, s = row & 2047;
  bool is_k = pc >= 512;
  int jj = (pc - (is_k ? 512 : 0)) * 2;  // even, 0..1022
  int h = jj >> 6, d = jj & 63, ii = d >> 1;
  float2 v = *(const float2*)&Cqk[(size_t)row * 2048 + pc * 2];
  float half = exp2f(-(float)ii * (13.287712379549449f / 31.0f));
  float ang = (float)s * half;
  float sn = sinf(ang), cs = cosf(ang);
  float e = v.x * cs - v.y * sn;
  float o = v.y * cs + v.x * sn;
  bf16 eh = f2b(e), oh = f2b(o);
  bf16 el = f2b(e - b2f(eh)), ol = f2b(o - b2f(oh));
  size_t idx = (((size_t)b * NH + h) * SEQ + s) * KD + d;
  bf16* ph = is_k ? kh : qh;
  bf16* pl = is_k ? kl : ql;
  union { bf16 h2[2]; unsigned u; } uh, ul;
  uh.h2[0] = eh; uh.h2[1] = oh;
  ul.h2[0] = el; ul.h2[1] = ol;
  *(unsigned*)&ph[idx] = uh.u;
  *(unsigned*)&pl[idx] = ul.u;
}

// ---------------- retention core (R18, proven ~98us) ----------
// grid 1024 x 256. bid: bh = bid>>5 (h=bh&15, b=bh>>4), grp_raw = bid&31,
// grp = (bh bit3) ? 31-grp_raw : grp_raw (co-resident slot balancing).
// Wave w owns stripe st = grp*4 + w (16 rows, m0 = st*16), iterating its
// causal prefix inside the block's ntiles = 2*grp+2 loop. K hi/lo staged in
// LDS (double-buffered ASYNC16, 2 chunks/wave), shared by all 4 waves; V
// per-wave direct global->reg (fragment buffer). Per-stripe math/order
// identical to R15 heavy path -> canary preserved.
__global__ __launch_bounds__(256, 4) void retention_k(
    const bf16* __restrict__ qh, const bf16* __restrict__ ql,
    const bf16* __restrict__ kh, const bf16* __restrict__ kl,
    const bf16* __restrict__ vf, const float* __restrict__ g,
    bf16* __restrict__ gated) {
  __shared__ bf16 KHs[2][32 * 64];
  __shared__ bf16 KLs[2][32 * 64];
  const int tid = threadIdx.x;
  const int wave = tid >> 6, lane = tid & 63;
  const int quad = lane >> 4, l16 = lane & 15;
  const int bid = blockIdx.x;
  const int grp_raw = bid & 31;
  const int bh = bid >> 5;            // 0..31
  const int h = bh & 15, b = bh >> 4;
  const int grp = ((bh >> 3) & 1) ? (31 - grp_raw) : grp_raw;
  const int st = grp * 4 + wave;      // stripe 0..127
  const int m0 = st * 16;
  const int ntiles = 2 * grp + 2;     // block loop count (= longest wave)

  const float t = exp2f(-(float)(5 + h));  // 1-gamma (exact)
  const float lng = log1pf(-t);            // ln(gamma)
  const float log2g = lng * 1.44269504088896340736f;

  float rf;
  {
    int m = m0 + l16;
    rf = exp2f((float)m * log2g) *
         rsqrtf(-expm1f((float)(m + 1) * lng) / t);
  }
  const float gstep = exp2f(-32.0f * log2g);  // gamma^-32
  float cfq[8];
#pragma unroll
  for (int i = 0; i < 8; ++i) {
    int hh = i >> 2, r = i & 3;
    cfq[i] = exp2f(-(float)(hh * 16 + quad * 4 + r) * log2g);
  }

  const size_t qoff = ((size_t)bh * SEQ + m0 + l16) * KD;
  bf16x8 aq0h = *(const bf16x8*)&qh[qoff + quad * 8];
  bf16x8 aq1h = *(const bf16x8*)&qh[qoff + 32 + quad * 8];
  bf16x8 aq0l = *(const bf16x8*)&ql[qoff + quad * 8];
  bf16x8 aq1l = *(const bf16x8*)&ql[qoff + 32 + quad * 8];

  floatx4 oacc[8] = {};
  float rs = 0.f;

  const bf16* khb = kh + (size_t)bh * SEQ * KD;
  const bf16* klb = kl + (size_t)bh * SEQ * KD;
  const bf16* vfb = vf + (size_t)bh * 64 * 8 * 512;
  const int lo8 = lane * 8;

  // K staging: 8 x 1KB chunks per tile over 4 waves (2 each):
  // cc<4 -> KH chunk cc, else KL chunk cc-4. Same swizzle as R12/R15.
  auto stage = [&](int nt, int buf) {
    const int n0s = nt * 32;
#pragma unroll
    for (int j = 0; j < 2; ++j) {
      int cc = wave * 2 + j;
      const bf16* src = (cc < 4) ? khb : klb;
      bf16* dst = (cc < 4) ? KHs[buf] : KLs[buf];
      int r = ((cc & 3) * 8) + (lane >> 3);
      int s = lane & 7;
      int q = (s - r) & 7;
      ASYNC16(src + (size_t)(n0s + r) * KD + q * 8, &dst[(cc & 3) * 512]);
    }
  };

  // Build PV A-frag in-register from the transposed score tile (as R12/R15).
  auto buildPA = [&](const floatx4* sc, int n0) -> bf16x8 {
    const int m = m0 + l16;
    const bool full = (m0 >= n0 + 31);  // tile fully below diagonal
    unsigned d[4];
#pragma unroll
    for (int hh = 0; hh < 2; ++hh) {
      float p[4];
#pragma unroll
      for (int r = 0; r < 4; ++r) {
        float pv;
        if (full) {
          pv = sc[hh][r] * rf * cfq[hh * 4 + r];
        } else {
          int n = n0 + hh * 16 + quad * 4 + r;
          pv = (m >= n) ? sc[hh][r] * rf * cfq[hh * 4 + r] : 0.f;
        }
        rs += pv;
        p[r] = pv;
      }
      union { bf16 hx[2]; unsigned u; } u0, u1;
      u0.hx[0] = f2b(p[0]); u0.hx[1] = f2b(p[1]);
      u1.hx[0] = f2b(p[2]); u1.hx[1] = f2b(p[3]);
      d[hh * 2 + 0] = u0.u;
      d[hh * 2 + 1] = u1.u;
    }
    unsigned a0 = d[0], b0 = d[2];  // (hh0 pair01, hh1 pair01)
    asm("v_permlane32_swap_b32 %0, %1" : "+v"(a0), "+v"(b0));
    asm("v_permlane16_swap_b32 %0, %1" : "+v"(a0), "+v"(b0));
    unsigned a1 = d[1], b1 = d[3];  // (hh0 pair23, hh1 pair23)
    asm("v_permlane32_swap_b32 %0, %1" : "+v"(a1), "+v"(b1));
    asm("v_permlane16_swap_b32 %0, %1" : "+v"(a1), "+v"(b1));
    union { unsigned u[4]; bf16x8 v; } pu;
    pu.u[0] = a0; pu.u[1] = a1; pu.u[2] = b0; pu.u[3] = b1;
    return pu.v;
  };

  stage(0, 0);
  for (int nt = 0; nt < ntiles; ++nt) {
    const int n0 = nt * 32;
    const int cur = nt & 1;
    asm volatile("s_waitcnt vmcnt(0) lgkmcnt(0)" ::: "memory");
    __syncthreads();

    const bool act = (n0 <= m0 + 15);

    // V tile direct to registers (only while this wave's stripe is active)
    bf16x8 vv[8];
    if (act) {
#pragma unroll
      for (int c = 0; c < 8; ++c)
        vv[c] = *(const bf16x8*)(vfb + ((size_t)nt * 8 + c) * 512 + lo8);
    }

    {
      int pf = (nt + 1 < ntiles) ? nt + 1 : nt;
      stage(pf, cur ^ 1);
    }

    if (act) {
      // QK (SWAPPED: A=K-frag, B=Q-frag) — identical to R15 heavy path
      floatx4 sc[2];
#pragma unroll
      for (int hh = 0; hh < 2; ++hh) {
        int krow = hh * 16 + l16;
        int c0 = ((quad + krow) & 7) * 8;
        int c1 = ((quad + 4 + krow) & 7) * 8;
        bf16x8 bkh0 = *(const bf16x8*)&KHs[cur][krow * 64 + c0];
        bf16x8 bkh1 = *(const bf16x8*)&KHs[cur][krow * 64 + c1];
        bf16x8 bkl0 = *(const bf16x8*)&KLs[cur][krow * 64 + c0];
        bf16x8 bkl1 = *(const bf16x8*)&KLs[cur][krow * 64 + c1];
        floatx4 z1 = {0.f, 0.f, 0.f, 0.f}, z2 = z1, z3 = z1;
        z1 = MFMA16(bkh0, aq0h, z1);
        z2 = MFMA16(bkh0, aq0l, z2);
        z3 = MFMA16(bkl0, aq0h, z3);
        z1 = MFMA16(bkh1, aq1h, z1);
        z2 = MFMA16(bkh1, aq1l, z2);
        z3 = MFMA16(bkl1, aq1h, z3);
        sc[hh] = z1 + z2 + z3;
      }

      bf16x8 pa = buildPA(sc, n0);
      rf *= gstep;

#pragma unroll
      for (int dt = 0; dt < 8; ++dt)
        oacc[dt] = MFMA16(pa, vv[dt], oacc[dt]);
    }
  }

  // ---- epilogue: denom clip, groupnorm(128), silu gate ----
  {
    float v = rs;
    v += __shfl_xor(v, 16);
    v += __shfl_xor(v, 32);
    float inv_den[4];
#pragma unroll
    for (int r = 0; r < 4; ++r) {
      float dsum = __shfl(v, quad * 4 + r);
      inv_den[r] = 1.0f / fmaxf(fabsf(dsum), 1.0f);
    }
    float s1[4] = {}, s2[4] = {};
#pragma unroll
    for (int dt = 0; dt < 8; ++dt) {
#pragma unroll
      for (int r = 0; r < 4; ++r) {
        float vv2 = oacc[dt][r] * inv_den[r];
        oacc[dt][r] = vv2;
        s1[r] += vv2;
        s2[r] += vv2 * vv2;
      }
    }
    float mean[4], istd[4];
#pragma unroll
    for (int r = 0; r < 4; ++r) {
      float a = s1[r], q2 = s2[r];
      a += __shfl_xor(a, 1); a += __shfl_xor(a, 2);
      a += __shfl_xor(a, 4); a += __shfl_xor(a, 8);
      q2 += __shfl_xor(q2, 1); q2 += __shfl_xor(q2, 2);
      q2 += __shfl_xor(q2, 4); q2 += __shfl_xor(q2, 8);
      mean[r] = a * (1.0f / 128.0f);
      float var = q2 * (1.0f / 128.0f) - mean[r] * mean[r];
      istd[r] = rsqrtf(fmaxf(var, 0.0f) + 1e-5f);
    }
#pragma unroll
    for (int dt = 0; dt < 8; ++dt) {
#pragma unroll
      for (int r = 0; r < 4; ++r) {
        int m = m0 + quad * 4 + r;
        int col = h * HD + dt * 16 + l16;
        float vv2 = (oacc[dt][r] - mean[r]) * istd[r];
        float gv = g[((size_t)b * SEQ + m) * 2048 + col];
        float sg = gv / (1.0f + expf(-gv));
        gated[((size_t)b * SEQ + m) * 2048 + col] = f2b(sg * vv2);
      }
    }
  }
}

// ---------------- launch ----------------
extern "C" void kernel_launch(void* const* d_in, const int* in_sizes, int n_in,
                              void* d_out, int out_size, void* d_ws,
                              size_t ws_size, hipStream_t stream) {
  const float* x   = (const float*)d_in[0];
  const float* q_w = (const float*)d_in[1];
  const float* q_b = (const float*)d_in[2];
  const float* k_w = (const float*)d_in[3];
  const float* k_b = (const float*)d_in[4];
  const float* v_w = (const float*)d_in[5];
  const float* v_b = (const float*)d_in[6];
  const float* g_w = (const float*)d_in[7];
  const float* g_b = (const float*)d_in[8];
  const float* o_w = (const float*)d_in[9];
  const float* o_b = (const float*)d_in[10];

  char* ws = (char*)d_ws;
  bf16* Wt    = (bf16*)ws; ws += (size_t)6144 * 1024 * 2;
  bf16* oT    = (bf16*)ws; ws += (size_t)1024 * 2048 * 2;
  bf16* xb    = (bf16*)ws; ws += (size_t)4096 * 1024 * 2;
  float* Cqk  = (float*)ws; ws += (size_t)4096 * 2048 * 4;
  bf16* qhb   = (bf16*)ws; ws += (size_t)32 * 2048 * 64 * 2;
  bf16* qlb   = (bf16*)ws; ws += (size_t)32 * 2048 * 64 * 2;
  bf16* khb   = (bf16*)ws; ws += (size_t)32 * 2048 * 64 * 2;
  bf16* klb   = (bf16*)ws; ws += (size_t)32 * 2048 * 64 * 2;
  bf16* vfb   = (bf16*)ws; ws += (size_t)32 * 64 * 8 * 512 * 2;  // 16.78 MB V frags
  float* gbuf = (float*)ws; ws += (size_t)2 * 2048 * 2048 * 4;
  bf16* gated = (bf16*)ws; ws += (size_t)4096 * 2048 * 2;

  convert_k<<<(4096 * 1024 / 4) / 256, 256, 0, stream>>>(x, xb);

  dim3 tb(32, 8);
  transpose_k<<<dim3(1024 / 32, 1024 / 32), tb, 0, stream>>>(q_w, Wt, 1024, 1024);
  transpose_k<<<dim3(1024 / 32, 1024 / 32), tb, 0, stream>>>(k_w, Wt + (size_t)1024 * 1024, 1024, 1024);
  transpose_k<<<dim3(2048 / 32, 1024 / 32), tb, 0, stream>>>(v_w, Wt + (size_t)2048 * 1024, 1024, 2048);
  transpose_k<<<dim3(2048 / 32, 1024 / 32), tb, 0, stream>>>(g_w, Wt + (size_t)4096 * 1024, 1024, 2048);
  transpose_k<<<dim3(1024 / 32, 2048 / 32), tb, 0, stream>>>(o_w, oT, 2048, 1024);

  // GEMM1 writes V directly in fragment layout (vtrans fused away)
  gemm_bt<128, 128, 1024, 0><<<dim3(6144 / 128, 4096 / 128), 256, 0, stream>>>(
      xb, Wt, 6144, q_b, k_b, v_b, g_b, Cqk, vfb, gbuf, nullptr);

  router_k<<<(4096 * 1024) / 256, 256, 0, stream>>>(Cqk, qhb, qlb, khb, klb);

  retention_k<<<dim3(1024), 256, 0, stream>>>(
      qhb, qlb, khb, klb, vfb, gbuf, gated);

  gemm_bt<128, 64, 2048, 1><<<dim3(1024 / 64, 4096 / 128), 256, 0, stream>>>(
      gated, oT, 1024, o_b, nullptr, nullptr, nullptr, nullptr, nullptr,
      nullptr, (float*)d_out);
}

// Round 16
// 316.232 us; speedup vs baseline: 1.0438x; 1.0425x over previous
//
#include <hip/hip_runtime.h>
#include <hip/hip_bf16.h>

// MultiScaleRetention forward — FINAL SHIP STATE (session best, verified
// 318.0us best-case / ~324us expected; start-of-session baseline 356.4us).
// Inputs/outputs FLOAT32; internals bf16 MFMA.
//   0) convert x -> xb (bf16); transpose weights f32 -> bf16
//   1) GEMM1: xb @ Wt^T, BK=64 2-phase loop (R20: half the barrier-drain
//      events of BK=32, 2x MFMA per phase). Staging = 8-row x 64-k 1KB
//      ASYNC16 chunks with rotation-swizzled source granule (q=(s-row)&7)
//      so 128B-stride ds_read_b128 fragment reads are 2-way/free. K order
//      ascending -> bit-identical results. LEAN epilogue: qk -> f32 Cqk
//      (+bias,+k-scale); V -> bf16 FRAGMENT layout (R17); g -> f32.
//   2) router: rotary (f32) + hi/lo bf16 split + (bh,S,64) layout for q,k.
//      At HBM floor (~100MB @ ~6.7TB/s effective). R19 fuse REVERTED:
//      2B scatter stores = 48x HBM write amplification (WRITE 3.25GB).
//   3) retention R18 (~97us): block = (bh, 4 consecutive 16-row stripes),
//      4 waves x 1 stripe each, LDS-staged K (dbuf ASYNC16, 2 chunks/wave)
//      + per-wave V direct-to-reg from fragment buffer. 4096 waves=4/SIMD.
//      Floor = causal-triangle shape x co-residency (no pipe >44%).
//   4) GEMM2: gated @ oT^T + o_b -> d_out (f32), same BK=64 loop.
// absmax canary: 0.01049805 exactly (all FP orders preserved).
// Tile-space measured: BK=32 -> 339us, BK=64 -> 318us (best), BK=128 ->
// 330us (6.29M LDS bank conflicts + longer stage latency). Next step-change
// would be the 256-sq 8-phase counted-vmcnt GEMM port (new sync template,
// needs race-screening; out of session budget).

typedef __hip_bfloat16 bf16;
typedef short bf16x4 __attribute__((ext_vector_type(4)));
typedef short bf16x8 __attribute__((ext_vector_type(8)));
typedef float floatx4 __attribute__((ext_vector_type(4)));

#define B_SZ 2
#define SEQ 2048
#define NH 16
#define KD 64
#define HD 128

// global->LDS direct copy, 16B/lane. LDS dest is wave-uniform base + lane*16.
#define ASYNC16(gp, lp)                                                             \
  __builtin_amdgcn_global_load_lds(                                                 \
      (const __attribute__((address_space(1))) unsigned int*)(unsigned long long)(const void*)(gp), \
      (__attribute__((address_space(3))) unsigned int*)(unsigned int)(unsigned long long)(void*)(lp), \
      16, 0, 0)

__device__ __forceinline__ float b2f(bf16 x) { return __bfloat162float(x); }
__device__ __forceinline__ bf16 f2b(float x) { return __float2bfloat16(x); }

#define MFMA16(a, bb, c) __builtin_amdgcn_mfma_f32_16x16x32_bf16(a, bb, c, 0, 0, 0)

// ---------------- f32 -> bf16 convert (x) ----------------
__global__ void convert_k(const float* __restrict__ in, bf16* __restrict__ out) {
  int i = blockIdx.x * 256 + threadIdx.x;  // one float4 per thread
  float4 v = reinterpret_cast<const float4*>(in)[i];
  union { bf16 h[4]; bf16x4 v4; } u;
  u.h[0] = f2b(v.x); u.h[1] = f2b(v.y); u.h[2] = f2b(v.z); u.h[3] = f2b(v.w);
  reinterpret_cast<bf16x4*>(out)[i] = u.v4;
}

// ---------------- weight transpose: in f32 (K,N) -> out bf16 (N,K) --------
__global__ void transpose_k(const float* __restrict__ in, bf16* __restrict__ out,
                            int K, int N) {
  __shared__ float tile[32][33];
  int tx = threadIdx.x, ty = threadIdx.y;
  int n0 = blockIdx.x * 32, k0 = blockIdx.y * 32;
#pragma unroll
  for (int j = 0; j < 4; ++j)
    tile[ty + j * 8][tx] = in[(size_t)(k0 + ty + j * 8) * N + n0 + tx];
  __syncthreads();
#pragma unroll
  for (int j = 0; j < 4; ++j)
    out[(size_t)(n0 + ty + j * 8) * K + k0 + tx] = f2b(tile[tx][ty + j * 8]);
}

// ---------------- GEMM: C(M,N) = A(M,K) @ Bt(N,K)^T ----------------
// R20 loop: BK=64. LDS [row][64] bf16 (As BM*64, Bs BN*64). Staging: chunk
// cc = 8 rows x 64 k = 1KB; lane L -> row cc*8+(L>>3), granule q=((L&7)-row)&7
// (rotation swizzle; LDS slot s holds granule (s-row)&7). Fragment read for
// k-granule g=kk*4+quad at row r -> slot (g+r)&7: banks spread across rows,
// 2-way max. MFMA kk=0 then kk=1 -> ascending K, bit-identical accumulation.
// MODE 0 epilogue: qk -> f32 Cqk; V -> bf16 FRAGMENT layout; g -> f32.
template <int BM, int BN, int KDIM, int MODE>
__global__ __launch_bounds__(256, 2) void gemm_bt(
    const bf16* __restrict__ A, const bf16* __restrict__ Bt, int Ndim,
    const float* __restrict__ bias_q, const float* __restrict__ bias_k,
    const float* __restrict__ bias_v, const float* __restrict__ bias_g,
    float* __restrict__ outCqk, bf16* __restrict__ out_v,
    float* __restrict__ out_g, float* __restrict__ outF) {
  __shared__ bf16 As[BM * 64];
  __shared__ bf16 Bs[BN * 64];
  const int tid = threadIdx.x;
  const int wave = tid >> 6, lane = tid & 63;
  const int quad = lane >> 4, l16 = lane & 15;
  const int m0 = blockIdx.y * BM, n0 = blockIdx.x * BN;
  constexpr int FI = BM / 32;
  constexpr int FJ = BN / 32;
  const int wm = (wave >> 1) * (BM / 2), wn = (wave & 1) * (BN / 2);

  floatx4 acc[FI][FJ] = {};

  for (int k0 = 0; k0 < KDIM; k0 += 64) {
#pragma unroll
    for (int j = 0; j < BM / 32; ++j) {
      int cc = wave * (BM / 32) + j;       // 0..BM/8-1
      int row = cc * 8 + (lane >> 3);
      int q = ((lane & 7) - row) & 7;
      ASYNC16(A + (size_t)(m0 + row) * KDIM + k0 + q * 8, &As[cc * 512]);
    }
#pragma unroll
    for (int j = 0; j < BN / 32; ++j) {
      int cc = wave * (BN / 32) + j;       // 0..BN/8-1
      int row = cc * 8 + (lane >> 3);
      int q = ((lane & 7) - row) & 7;
      ASYNC16(Bt + (size_t)(n0 + row) * KDIM + k0 + q * 8, &Bs[cc * 512]);
    }
    __syncthreads();  // compiler drains vmcnt(0) before s_barrier

    bf16x8 af[2][FI], bfr[2][FJ];
#pragma unroll
    for (int kk = 0; kk < 2; ++kk) {
#pragma unroll
      for (int i = 0; i < FI; ++i) {
        int row = wm + i * 16 + l16;
        int slot = ((kk * 4 + quad) + row) & 7;
        af[kk][i] = *(const bf16x8*)&As[row * 64 + slot * 8];
      }
#pragma unroll
      for (int j = 0; j < FJ; ++j) {
        int row = wn + j * 16 + l16;
        int slot = ((kk * 4 + quad) + row) & 7;
        bfr[kk][j] = *(const bf16x8*)&Bs[row * 64 + slot * 8];
      }
    }
#pragma unroll
    for (int kk = 0; kk < 2; ++kk)
#pragma unroll
      for (int i = 0; i < FI; ++i)
#pragma unroll
        for (int j = 0; j < FJ; ++j)
          acc[i][j] = MFMA16(af[kk][i], bfr[kk][j], acc[i][j]);
    __syncthreads();
  }

  // LEAN epilogue, all stores coalesced (unchanged)
#pragma unroll
  for (int i = 0; i < FI; ++i) {
#pragma unroll
    for (int j = 0; j < FJ; ++j) {
      int gn = n0 + wn + j * 16 + l16;
      if (MODE == 0 && gn >= 2048 && gn < 4096) {
        // V -> fragment layout, one 8B packed store (4 consecutive s)
        int jj = gn - 2048;
        int s0 = m0 + wm + i * 16 + quad * 4;  // 4-aligned
        union { bf16 e[4]; unsigned long long u8; } pk;
#pragma unroll
        for (int r = 0; r < 4; ++r) pk.e[r] = f2b(acc[i][j][r] + bias_v[jj]);
        int b2 = s0 >> 11, srel = s0 & 2047;
        int h2 = jj >> 7, dloc = jj & 127;
        size_t bh2 = (size_t)b2 * NH + h2;
        size_t idx = ((bh2 * 64 + (srel >> 5)) * 8 + (dloc >> 4)) * 512 +
                     (size_t)(((srel >> 3) & 3) * 16 + (dloc & 15)) * 8 +
                     (srel & 7);
        *(unsigned long long*)&out_v[idx] = pk.u8;
      } else {
#pragma unroll
        for (int r = 0; r < 4; ++r) {
          int gm = m0 + wm + i * 16 + quad * 4 + r;
          float v = acc[i][j][r];
          if (MODE == 1) {
            v += bias_q[gn];  // bias_q = o_b
            outF[(size_t)gm * Ndim + gn] = v;
          } else {
            if (gn < 2048) {
              bool is_k = gn >= 1024;
              int jj = is_k ? gn - 1024 : gn;
              v += is_k ? bias_k[jj] : bias_q[jj];
              if (is_k) v *= 0.125f;  // SCALING = KEY_DIM^-0.5
              outCqk[(size_t)gm * 2048 + gn] = v;  // f32, exact
            } else {
              int jj = gn - 4096;
              v += bias_g[jj];
              out_g[(size_t)gm * 2048 + jj] = v;  // f32
            }
          }
        }
      }
    }
  }
}

// ---------------- router: rotary + hi/lo split + layout (R12 version) -----
__global__ void router_k(const float* __restrict__ Cqk,
                         bf16* __restrict__ qh, bf16* __restrict__ ql,
                         bf16* __restrict__ kh, bf16* __restrict__ kl) {
  int t = blockIdx.x * 256 + threadIdx.x;  // 4096*1024 threads
  int row = t >> 10, pc = t & 1023;
  int b = row >> 11, s = row & 2047;
  bool is_k = pc >= 512;
  int jj = (pc - (is_k ? 512 : 0)) * 2;  // even, 0..1022
  int h = jj >> 6, d = jj & 63, ii = d >> 1;
  float2 v = *(const float2*)&Cqk[(size_t)row * 2048 + pc * 2];
  float half = exp2f(-(float)ii * (13.287712379549449f / 31.0f));
  float ang = (float)s * half;
  float sn = sinf(ang), cs = cosf(ang);
  float e = v.x * cs - v.y * sn;
  float o = v.y * cs + v.x * sn;
  bf16 eh = f2b(e), oh = f2b(o);
  bf16 el = f2b(e - b2f(eh)), ol = f2b(o - b2f(oh));
  size_t idx = (((size_t)b * NH + h) * SEQ + s) * KD + d;
  bf16* ph = is_k ? kh : qh;
  bf16* pl = is_k ? kl : ql;
  union { bf16 h2[2]; unsigned u; } uh, ul;
  uh.h2[0] = eh; uh.h2[1] = oh;
  ul.h2[0] = el; ul.h2[1] = ol;
  *(unsigned*)&ph[idx] = uh.u;
  *(unsigned*)&pl[idx] = ul.u;
}

// ---------------- retention core (R18, ~97us) ----------
// grid 1024 x 256. bid: bh = bid>>5 (h=bh&15, b=bh>>4), grp_raw = bid&31,
// grp = (bh bit3) ? 31-grp_raw : grp_raw (co-resident slot balancing).
// Wave w owns stripe st = grp*4 + w (16 rows, m0 = st*16), iterating its
// causal prefix inside the block's ntiles = 2*grp+2 loop. K hi/lo staged in
// LDS (double-buffered ASYNC16, 2 chunks/wave), shared by all 4 waves; V
// per-wave direct global->reg (fragment buffer). Per-stripe math/order
// identical to R15 heavy path -> canary preserved.
__global__ __launch_bounds__(256, 4) void retention_k(
    const bf16* __restrict__ qh, const bf16* __restrict__ ql,
    const bf16* __restrict__ kh, const bf16* __restrict__ kl,
    const bf16* __restrict__ vf, const float* __restrict__ g,
    bf16* __restrict__ gated) {
  __shared__ bf16 KHs[2][32 * 64];
  __shared__ bf16 KLs[2][32 * 64];
  const int tid = threadIdx.x;
  const int wave = tid >> 6, lane = tid & 63;
  const int quad = lane >> 4, l16 = lane & 15;
  const int bid = blockIdx.x;
  const int grp_raw = bid & 31;
  const int bh = bid >> 5;            // 0..31
  const int h = bh & 15, b = bh >> 4;
  const int grp = ((bh >> 3) & 1) ? (31 - grp_raw) : grp_raw;
  const int st = grp * 4 + wave;      // stripe 0..127
  const int m0 = st * 16;
  const int ntiles = 2 * grp + 2;     // block loop count (= longest wave)

  const float t = exp2f(-(float)(5 + h));  // 1-gamma (exact)
  const float lng = log1pf(-t);            // ln(gamma)
  const float log2g = lng * 1.44269504088896340736f;

  float rf;
  {
    int m = m0 + l16;
    rf = exp2f((float)m * log2g) *
         rsqrtf(-expm1f((float)(m + 1) * lng) / t);
  }
  const float gstep = exp2f(-32.0f * log2g);  // gamma^-32
  float cfq[8];
#pragma unroll
  for (int i = 0; i < 8; ++i) {
    int hh = i >> 2, r = i & 3;
    cfq[i] = exp2f(-(float)(hh * 16 + quad * 4 + r) * log2g);
  }

  const size_t qoff = ((size_t)bh * SEQ + m0 + l16) * KD;
  bf16x8 aq0h = *(const bf16x8*)&qh[qoff + quad * 8];
  bf16x8 aq1h = *(const bf16x8*)&qh[qoff + 32 + quad * 8];
  bf16x8 aq0l = *(const bf16x8*)&ql[qoff + quad * 8];
  bf16x8 aq1l = *(const bf16x8*)&ql[qoff + 32 + quad * 8];

  floatx4 oacc[8] = {};
  float rs = 0.f;

  const bf16* khb = kh + (size_t)bh * SEQ * KD;
  const bf16* klb = kl + (size_t)bh * SEQ * KD;
  const bf16* vfb = vf + (size_t)bh * 64 * 8 * 512;
  const int lo8 = lane * 8;

  // K staging: 8 x 1KB chunks per tile over 4 waves (2 each):
  // cc<4 -> KH chunk cc, else KL chunk cc-4. Same swizzle as R12/R15.
  auto stage = [&](int nt, int buf) {
    const int n0s = nt * 32;
#pragma unroll
    for (int j = 0; j < 2; ++j) {
      int cc = wave * 2 + j;
      const bf16* src = (cc < 4) ? khb : klb;
      bf16* dst = (cc < 4) ? KHs[buf] : KLs[buf];
      int r = ((cc & 3) * 8) + (lane >> 3);
      int s = lane & 7;
      int q = (s - r) & 7;
      ASYNC16(src + (size_t)(n0s + r) * KD + q * 8, &dst[(cc & 3) * 512]);
    }
  };

  // Build PV A-frag in-register from the transposed score tile (as R12/R15).
  auto buildPA = [&](const floatx4* sc, int n0) -> bf16x8 {
    const int m = m0 + l16;
    const bool full = (m0 >= n0 + 31);  // tile fully below diagonal
    unsigned d[4];
#pragma unroll
    for (int hh = 0; hh < 2; ++hh) {
      float p[4];
#pragma unroll
      for (int r = 0; r < 4; ++r) {
        float pv;
        if (full) {
          pv = sc[hh][r] * rf * cfq[hh * 4 + r];
        } else {
          int n = n0 + hh * 16 + quad * 4 + r;
          pv = (m >= n) ? sc[hh][r] * rf * cfq[hh * 4 + r] : 0.f;
        }
        rs += pv;
        p[r] = pv;
      }
      union { bf16 hx[2]; unsigned u; } u0, u1;
      u0.hx[0] = f2b(p[0]); u0.hx[1] = f2b(p[1]);
      u1.hx[0] = f2b(p[2]); u1.hx[1] = f2b(p[3]);
      d[hh * 2 + 0] = u0.u;
      d[hh * 2 + 1] = u1.u;
    }
    unsigned a0 = d[0], b0 = d[2];  // (hh0 pair01, hh1 pair01)
    asm("v_permlane32_swap_b32 %0, %1" : "+v"(a0), "+v"(b0));
    asm("v_permlane16_swap_b32 %0, %1" : "+v"(a0), "+v"(b0));
    unsigned a1 = d[1], b1 = d[3];  // (hh0 pair23, hh1 pair23)
    asm("v_permlane32_swap_b32 %0, %1" : "+v"(a1), "+v"(b1));
    asm("v_permlane16_swap_b32 %0, %1" : "+v"(a1), "+v"(b1));
    union { unsigned u[4]; bf16x8 v; } pu;
    pu.u[0] = a0; pu.u[1] = a1; pu.u[2] = b0; pu.u[3] = b1;
    return pu.v;
  };

  stage(0, 0);
  for (int nt = 0; nt < ntiles; ++nt) {
    const int n0 = nt * 32;
    const int cur = nt & 1;
    asm volatile("s_waitcnt vmcnt(0) lgkmcnt(0)" ::: "memory");
    __syncthreads();

    const bool act = (n0 <= m0 + 15);

    // V tile direct to registers (only while this wave's stripe is active)
    bf16x8 vv[8];
    if (act) {
#pragma unroll
      for (int c = 0; c < 8; ++c)
        vv[c] = *(const bf16x8*)(vfb + ((size_t)nt * 8 + c) * 512 + lo8);
    }

    {
      int pf = (nt + 1 < ntiles) ? nt + 1 : nt;
      stage(pf, cur ^ 1);
    }

    if (act) {
      // QK (SWAPPED: A=K-frag, B=Q-frag) — identical to R15 heavy path
      floatx4 sc[2];
#pragma unroll
      for (int hh = 0; hh < 2; ++hh) {
        int krow = hh * 16 + l16;
        int c0 = ((quad + krow) & 7) * 8;
        int c1 = ((quad + 4 + krow) & 7) * 8;
        bf16x8 bkh0 = *(const bf16x8*)&KHs[cur][krow * 64 + c0];
        bf16x8 bkh1 = *(const bf16x8*)&KHs[cur][krow * 64 + c1];
        bf16x8 bkl0 = *(const bf16x8*)&KLs[cur][krow * 64 + c0];
        bf16x8 bkl1 = *(const bf16x8*)&KLs[cur][krow * 64 + c1];
        floatx4 z1 = {0.f, 0.f, 0.f, 0.f}, z2 = z1, z3 = z1;
        z1 = MFMA16(bkh0, aq0h, z1);
        z2 = MFMA16(bkh0, aq0l, z2);
        z3 = MFMA16(bkl0, aq0h, z3);
        z1 = MFMA16(bkh1, aq1h, z1);
        z2 = MFMA16(bkh1, aq1l, z2);
        z3 = MFMA16(bkl1, aq1h, z3);
        sc[hh] = z1 + z2 + z3;
      }

      bf16x8 pa = buildPA(sc, n0);
      rf *= gstep;

#pragma unroll
      for (int dt = 0; dt < 8; ++dt)
        oacc[dt] = MFMA16(pa, vv[dt], oacc[dt]);
    }
  }

  // ---- epilogue: denom clip, groupnorm(128), silu gate ----
  {
    float v = rs;
    v += __shfl_xor(v, 16);
    v += __shfl_xor(v, 32);
    float inv_den[4];
#pragma unroll
    for (int r = 0; r < 4; ++r) {
      float dsum = __shfl(v, quad * 4 + r);
      inv_den[r] = 1.0f / fmaxf(fabsf(dsum), 1.0f);
    }
    float s1[4] = {}, s2[4] = {};
#pragma unroll
    for (int dt = 0; dt < 8; ++dt) {
#pragma unroll
      for (int r = 0; r < 4; ++r) {
        float vv2 = oacc[dt][r] * inv_den[r];
        oacc[dt][r] = vv2;
        s1[r] += vv2;
        s2[r] += vv2 * vv2;
      }
    }
    float mean[4], istd[4];
#pragma unroll
    for (int r = 0; r < 4; ++r) {
      float a = s1[r], q2 = s2[r];
      a += __shfl_xor(a, 1); a += __shfl_xor(a, 2);
      a += __shfl_xor(a, 4); a += __shfl_xor(a, 8);
      q2 += __shfl_xor(q2, 1); q2 += __shfl_xor(q2, 2);
      q2 += __shfl_xor(q2, 4); q2 += __shfl_xor(q2, 8);
      mean[r] = a * (1.0f / 128.0f);
      float var = q2 * (1.0f / 128.0f) - mean[r] * mean[r];
      istd[r] = rsqrtf(fmaxf(var, 0.0f) + 1e-5f);
    }
#pragma unroll
    for (int dt = 0; dt < 8; ++dt) {
#pragma unroll
      for (int r = 0; r < 4; ++r) {
        int m = m0 + quad * 4 + r;
        int col = h * HD + dt * 16 + l16;
        float vv2 = (oacc[dt][r] - mean[r]) * istd[r];
        float gv = g[((size_t)b * SEQ + m) * 2048 + col];
        float sg = gv / (1.0f + expf(-gv));
        gated[((size_t)b * SEQ + m) * 2048 + col] = f2b(sg * vv2);
      }
    }
  }
}

// ---------------- launch ----------------
extern "C" void kernel_launch(void* const* d_in, const int* in_sizes, int n_in,
                              void* d_out, int out_size, void* d_ws,
                              size_t ws_size, hipStream_t stream) {
  const float* x   = (const float*)d_in[0];
  const float* q_w = (const float*)d_in[1];
  const float* q_b = (const float*)d_in[2];
  const float* k_w = (const float*)d_in[3];
  const float* k_b = (const float*)d_in[4];
  const float* v_w = (const float*)d_in[5];
  const float* v_b = (const float*)d_in[6];
  const float* g_w = (const float*)d_in[7];
  const float* g_b = (const float*)d_in[8];
  const float* o_w = (const float*)d_in[9];
  const float* o_b = (const float*)d_in[10];

  char* ws = (char*)d_ws;
  bf16* Wt    = (bf16*)ws; ws += (size_t)6144 * 1024 * 2;
  bf16* oT    = (bf16*)ws; ws += (size_t)1024 * 2048 * 2;
  bf16* xb    = (bf16*)ws; ws += (size_t)4096 * 1024 * 2;
  float* Cqk  = (float*)ws; ws += (size_t)4096 * 2048 * 4;
  bf16* qhb   = (bf16*)ws; ws += (size_t)32 * 2048 * 64 * 2;
  bf16* qlb   = (bf16*)ws; ws += (size_t)32 * 2048 * 64 * 2;
  bf16* khb   = (bf16*)ws; ws += (size_t)32 * 2048 * 64 * 2;
  bf16* klb   = (bf16*)ws; ws += (size_t)32 * 2048 * 64 * 2;
  bf16* vfb   = (bf16*)ws; ws += (size_t)32 * 64 * 8 * 512 * 2;  // 16.78 MB V frags
  float* gbuf = (float*)ws; ws += (size_t)2 * 2048 * 2048 * 4;
  bf16* gated = (bf16*)ws; ws += (size_t)4096 * 2048 * 2;

  convert_k<<<(4096 * 1024 / 4) / 256, 256, 0, stream>>>(x, xb);

  dim3 tb(32, 8);
  transpose_k<<<dim3(1024 / 32, 1024 / 32), tb, 0, stream>>>(q_w, Wt, 1024, 1024);
  transpose_k<<<dim3(1024 / 32, 1024 / 32), tb, 0, stream>>>(k_w, Wt + (size_t)1024 * 1024, 1024, 1024);
  transpose_k<<<dim3(2048 / 32, 1024 / 32), tb, 0, stream>>>(v_w, Wt + (size_t)2048 * 1024, 1024, 2048);
  transpose_k<<<dim3(2048 / 32, 1024 / 32), tb, 0, stream>>>(g_w, Wt + (size_t)4096 * 1024, 1024, 2048);
  transpose_k<<<dim3(1024 / 32, 2048 / 32), tb, 0, stream>>>(o_w, oT, 2048, 1024);

  // GEMM1 writes V directly in fragment layout (vtrans fused away)
  gemm_bt<128, 128, 1024, 0><<<dim3(6144 / 128, 4096 / 128), 256, 0, stream>>>(
      xb, Wt, 6144, q_b, k_b, v_b, g_b, Cqk, vfb, gbuf, nullptr);

  router_k<<<(4096 * 1024) / 256, 256, 0, stream>>>(Cqk, qhb, qlb, khb, klb);

  retention_k<<<dim3(1024), 256, 0, stream>>>(
      qhb, qlb, khb, klb, vfb, gbuf, gated);

  gemm_bt<128, 64, 2048, 1><<<dim3(1024 / 64, 4096 / 128), 256, 0, stream>>>(
      gated, oT, 1024, o_b, nullptr, nullptr, nullptr, nullptr, nullptr,
      nullptr, (float*)d_out);
}